// Round 1
// baseline (194.569 us; speedup 1.0000x reference)
//
#include <hip/hip_runtime.h>

#define BB 32
#define CC 64
#define NN 1024

typedef __attribute__((ext_vector_type(8))) short bf8;            // 8 bf16 = 4 VGPR (MFMA A/B frag)
typedef __attribute__((ext_vector_type(4))) float f4;             // MFMA C/D frag
typedef __attribute__((ext_vector_type(4))) unsigned short us4;   // 8B packed bf16 store

__device__ __forceinline__ unsigned short f2bf(float f) {
    unsigned u = __float_as_uint(f);
    return (unsigned short)((u + 0x7fffu + ((u >> 16) & 1u)) >> 16);
}
__device__ __forceinline__ float bf2f(unsigned short u) {
    return __uint_as_float(((unsigned)u) << 16);
}

#define MFMA(a, b, c) __builtin_amdgcn_mfma_f32_16x16x32_bf16(a, b, c, 0, 0, 0)

// ---------------------------------------------------------------------------
// k0: merged prep. Blocks 0-1023: w_mk (1M fp32) -> bf16 (layout unchanged).
// Blocks 1024-1039: wcat_bf[192][64] = stacked bf16 weights (rows 0-63
// w_theta, 64-127 w_phi, 128-191 w_mv@w_g); wmask -> bf16.
// ---------------------------------------------------------------------------
__global__ void k0_prep(const float* __restrict__ w_mv, const float* __restrict__ w_g,
                        const float* __restrict__ w_theta, const float* __restrict__ w_phi,
                        const float* __restrict__ w_mask, const float* __restrict__ w_mk,
                        unsigned short* __restrict__ wcat_bf,
                        unsigned short* __restrict__ wmask_bf,
                        unsigned short* __restrict__ wmk_bf) {
    int tid = threadIdx.x;
    if (blockIdx.x < 1024) {
        int i = (blockIdx.x * 256 + tid) * 4;
        float4 v = *(const float4*)(w_mk + i);
        us4 r;
        r.x = f2bf(v.x); r.y = f2bf(v.y); r.z = f2bf(v.z); r.w = f2bf(v.w);
        *(us4*)(wmk_bf + i) = r;
    } else {
        int idx = (blockIdx.x - 1024) * 256 + tid;
        int d = idx >> 6, e = idx & 63;
        float acc = 0.f;
        for (int c = 0; c < 64; ++c) acc += w_mv[d * 64 + c] * w_g[c * 64 + e];
        wcat_bf[idx] = f2bf(w_theta[idx]);
        wcat_bf[4096 + idx] = f2bf(w_phi[idx]);
        wcat_bf[8192 + idx] = f2bf(acc);
        wmask_bf[idx] = f2bf(w_mask[idx]);
    }
}

// ---------------------------------------------------------------------------
// k1: channel GEMMs via MFMA: out[192][64-tile] = wcat @ x_tile (K=c=64).
// x tile staged transposed+bf16 in LDS (pad 66). theta (rows 0-63) stores
// transposed [n][c] as contiguous us4; phi/g2 store [c][n].
// grid (16, B), 256 thr / 4 waves; wave w -> wcat rows [48w, 48w+48).
// ---------------------------------------------------------------------------
__global__ __launch_bounds__(256, 4) void k1_channel(const float* __restrict__ x,
                                                     const unsigned short* __restrict__ wcat,
                                                     unsigned short* __restrict__ theta_nc,
                                                     unsigned short* __restrict__ phi_cm,
                                                     unsigned short* __restrict__ g2_cm) {
    __shared__ unsigned short xT[64][66];
    int b = blockIdx.y;
    int n0 = blockIdx.x * 64;
    int tid = threadIdx.x;
    int w = tid >> 6, lane = tid & 63, l16 = lane & 15, q = lane >> 4;
    size_t bo = (size_t)b * CC * NN;
#pragma unroll
    for (int i = 0; i < 16; ++i) {
        int idx = i * 256 + tid;
        int c = idx >> 6, n2 = idx & 63;
        xT[n2][c] = f2bf(x[bo + (size_t)c * NN + n0 + n2]);
    }
    __syncthreads();
    // B-frags: lane's n-col = ct*16+l16, k=c contiguous 8 at q*8 (+32)
    bf8 bF[4][2];
#pragma unroll
    for (int ct = 0; ct < 4; ++ct) {
        bF[ct][0] = *(const bf8*)&xT[ct * 16 + l16][q * 8];
        bF[ct][1] = *(const bf8*)&xT[ct * 16 + l16][32 + q * 8];
    }
#pragma unroll
    for (int rt = 0; rt < 3; ++rt) {
        int R = w * 48 + rt * 16;  // wcat row-tile base (16-aligned, within one output)
        const unsigned short* wa = wcat + (R + l16) * 64 + q * 8;
        bf8 a0 = *(const bf8*)wa;
        bf8 a1 = *(const bf8*)(wa + 32);
        int which = R >> 6, rb = R & 63;  // wave-uniform
#pragma unroll
        for (int ct = 0; ct < 4; ++ct) {
            f4 acc = {0.f, 0.f, 0.f, 0.f};
            acc = MFMA(a0, bF[ct][0], acc);
            acc = MFMA(a1, bF[ct][1], acc);
            int n = n0 + ct * 16 + l16;
            if (which == 0) {  // theta: [n][c] layout, rows o contiguous per lane
                us4 t;
                t.x = f2bf(acc[0]); t.y = f2bf(acc[1]);
                t.z = f2bf(acc[2]); t.w = f2bf(acc[3]);
                *(us4*)&theta_nc[bo + (size_t)n * 64 + rb + q * 4] = t;
            } else {
                unsigned short* dst = (which == 1 ? phi_cm : g2_cm) + bo;
#pragma unroll
                for (int r = 0; r < 4; ++r)
                    dst[(size_t)(rb + q * 4 + r) * NN + n] = f2bf(acc[r]);
            }
        }
    }
}

// ---------------------------------------------------------------------------
// k2: phi2t[b][k][c] = sum_m wmk[k][m] * phi_cm[c][m]  (MFMA, K=m=1024)
// 512 thr / 8 waves: (ks = w&3 -> 16 k-rows, mh = w>>2 -> m-half).
// NO LDS staging: phi per batch = 128 KB (L2-resident, shared by 16 blocks);
// A rows (wmk) and B frags (phi) load straight from global -> barrier-free
// main loop, compiler software-pipelines across mc iterations.
// ---------------------------------------------------------------------------
__global__ __launch_bounds__(512, 4) void k2_phi2(const unsigned short* __restrict__ phi_cm,
                                                  const unsigned short* __restrict__ wmk_bf,
                                                  unsigned short* __restrict__ phi2t) {
    __shared__ float red[64][68];
    int b = blockIdx.y;
    int k0 = blockIdx.x * 64;
    int tid = threadIdx.x;
    int w = tid >> 6, lane = tid & 63, l16 = lane & 15, q = lane >> 4;
    int ks = w & 3, mh = w >> 2;
    size_t bo = (size_t)b * CC * NN;
    const unsigned short* phib = phi_cm + bo + q * 8;
    const unsigned short* arow = wmk_bf + (size_t)(k0 + ks * 16 + l16) * NN + q * 8;
    f4 acc[4];
#pragma unroll
    for (int tc = 0; tc < 4; ++tc) acc[tc] = (f4){0.f, 0.f, 0.f, 0.f};

#pragma unroll 2
    for (int mc = 0; mc < 8; ++mc) {
        int m0 = mh * 512 + mc * 64;
        bf8 a0 = *(const bf8*)(arow + m0);
        bf8 a1 = *(const bf8*)(arow + m0 + 32);
#pragma unroll
        for (int tc = 0; tc < 4; ++tc) {
            const unsigned short* bp = phib + (size_t)(tc * 16 + l16) * NN + m0;
            bf8 b0 = *(const bf8*)bp;
            bf8 b1 = *(const bf8*)(bp + 32);
            acc[tc] = MFMA(a0, b0, acc[tc]);
            acc[tc] = MFMA(a1, b1, acc[tc]);
        }
    }
    // cross-half reduction via LDS
    if (mh == 1) {
#pragma unroll
        for (int tc = 0; tc < 4; ++tc)
#pragma unroll
            for (int r = 0; r < 4; ++r) red[ks * 16 + q * 4 + r][tc * 16 + l16] = acc[tc][r];
    }
    __syncthreads();
    if (mh == 0) {
        unsigned short* prow = phi2t + bo;
#pragma unroll
        for (int tc = 0; tc < 4; ++tc)
#pragma unroll
            for (int r = 0; r < 4; ++r) {
                float v = acc[tc][r] + red[ks * 16 + q * 4 + r][tc * 16 + l16];
                prow[(size_t)(k0 + ks * 16 + q * 4 + r) * 64 + tc * 16 + l16] = f2bf(v);
            }
    }
}

// ---------------------------------------------------------------------------
// k3: S[k] = sum_n exp(att2[n][k]), att2 = theta @ phi2t^T (K=64), then
// g3[c][k] = g2[c][k] / S[k]. 512 thr / 8 waves: (wq -> n offset, nh -> n-half).
// theta rows are wave-private -> register double-buffer prefetch (8 VGPRs).
// No max subtraction: |att2| <~ 45 << 88 (fp32 exp range).
// ---------------------------------------------------------------------------
__global__ __launch_bounds__(512, 4) void k3_stats(const unsigned short* __restrict__ theta_nc,
                                                   const unsigned short* __restrict__ phi2t,
                                                   const unsigned short* __restrict__ g2_cm,
                                                   unsigned short* __restrict__ g3_cm) {
    __shared__ float sred[8][64];
    __shared__ float svs[64];
    int b = blockIdx.y;
    int k0 = blockIdx.x * 64;
    int tid = threadIdx.x;
    int w = tid >> 6, lane = tid & 63, l16 = lane & 15, q = lane >> 4;
    int wq = w & 3, nh = w >> 2;
    size_t bo = (size_t)b * CC * NN;
    bf8 bF[4][2];
#pragma unroll
    for (int tc = 0; tc < 4; ++tc)
#pragma unroll
        for (int kc = 0; kc < 2; ++kc)
            bF[tc][kc] = *(const bf8*)(phi2t + bo + (size_t)(k0 + tc * 16 + l16) * 64 + kc * 32 + q * 8);
    float s[4] = {0.f, 0.f, 0.f, 0.f};
    const unsigned short* thb = theta_nc + bo + q * 8;
    int nbase = nh * 8;
    int nrow0 = (nbase + 0) * 64 + wq * 16 + l16;
    bf8 a0 = *(const bf8*)(thb + (size_t)nrow0 * 64);
    bf8 a1 = *(const bf8*)(thb + (size_t)nrow0 * 64 + 32);
    for (int nb = 0; nb < 8; ++nb) {
        bf8 p0, p1;
        if (nb < 7) {  // prefetch next chunk while computing this one
            int nr = (nbase + nb + 1) * 64 + wq * 16 + l16;
            p0 = *(const bf8*)(thb + (size_t)nr * 64);
            p1 = *(const bf8*)(thb + (size_t)nr * 64 + 32);
        }
#pragma unroll
        for (int tc = 0; tc < 4; ++tc) {
            f4 acc = {0.f, 0.f, 0.f, 0.f};
            acc = MFMA(a0, bF[tc][0], acc);
            acc = MFMA(a1, bF[tc][1], acc);
            s[tc] += __expf(acc[0]) + __expf(acc[1]) + __expf(acc[2]) + __expf(acc[3]);
        }
        a0 = p0;
        a1 = p1;
    }
#pragma unroll
    for (int tc = 0; tc < 4; ++tc) {
        s[tc] += __shfl_xor(s[tc], 16, 64);
        s[tc] += __shfl_xor(s[tc], 32, 64);
    }
    if (q == 0) {
#pragma unroll
        for (int tc = 0; tc < 4; ++tc) sred[w][tc * 16 + l16] = s[tc];
    }
    __syncthreads();
    if (tid < 64) {
        float S = 0.f;
#pragma unroll
        for (int ww = 0; ww < 8; ++ww) S += sred[ww][tid];
        svs[tid] = 1.f / S;
    }
    __syncthreads();
    int c0 = tid >> 6, kl = tid & 63;
#pragma unroll
    for (int i = 0; i < 8; ++i) {
        int c = c0 * 8 + i;
        size_t ix = bo + (size_t)c * NN + k0 + kl;
        g3_cm[ix] = f2bf(bf2f(g2_cm[ix]) * svs[kl]);
    }
}

// ---------------------------------------------------------------------------
// k4: per (b, n-tile 64): attT[m][n] = phi2t @ theta^T, P = exp(attT) (Sinv in
// g3), P -> LDS (wave-private rows), outT[c][n] += g3 @ P^T; halves reduce via
// LDS; epilogue finalT = wmask @ outT + x.
// NO LDS staging: phi2t/g3 per batch = 128 KB each (L2-resident, shared by 16
// blocks); A and G frags load straight from global -> the m-loop has ZERO
// barriers (P_lds rows are wave-private). 512 thr / 8 waves:
// (ws = w&3 -> 16 n's, mh = w>>2 -> m-half).
// ---------------------------------------------------------------------------
__global__ __launch_bounds__(512, 4) void k4_out(const unsigned short* __restrict__ theta_nc,
                                                 const unsigned short* __restrict__ phi2t,
                                                 const unsigned short* __restrict__ g3_cm,
                                                 const unsigned short* __restrict__ wmask_bf,
                                                 const float* __restrict__ x,
                                                 float* __restrict__ out) {
    __shared__ unsigned short P_lds[2][64][72];
    __shared__ float o_red[64][68];
    __shared__ unsigned short o_lds[64][72];
    int b = blockIdx.y;
    int n0 = blockIdx.x * 64;
    int tid = threadIdx.x;
    int w = tid >> 6, lane = tid & 63, l16 = lane & 15, q = lane >> 4;
    int ws = w & 3, mh = w >> 2;
    int nl = ws * 16 + l16;  // lane's n (LDS row, frag col) — wave-private rows
    size_t bo = (size_t)b * CC * NN;
    bf8 thB[2];
#pragma unroll
    for (int kc = 0; kc < 2; ++kc)
        thB[kc] = *(const bf8*)(theta_nc + bo + (size_t)(n0 + nl) * 64 + kc * 32 + q * 8);
    f4 accO[4];
#pragma unroll
    for (int tr = 0; tr < 4; ++tr) accO[tr] = (f4){0.f, 0.f, 0.f, 0.f};
    const unsigned short* p2b = phi2t + bo + q * 8;
    const unsigned short* g3b = g3_cm + bo + q * 8;

#pragma unroll 2
    for (int mc = 0; mc < 8; ++mc) {
        int m0 = mh * 512 + mc * 64;
        // GEMM1: attT tile (rows m, cols n), A = phi2t rows direct from L2;
        // exp -> P_lds[mh][n][m-local]
#pragma unroll
        for (int tr = 0; tr < 4; ++tr) {
            const unsigned short* ap = p2b + (size_t)(m0 + tr * 16 + l16) * 64;
            bf8 a0 = *(const bf8*)ap;
            bf8 a1 = *(const bf8*)(ap + 32);
            f4 at = {0.f, 0.f, 0.f, 0.f};
            at = MFMA(a0, thB[0], at);
            at = MFMA(a1, thB[1], at);
            us4 pk;
            pk.x = f2bf(__expf(at[0]));
            pk.y = f2bf(__expf(at[1]));
            pk.z = f2bf(__expf(at[2]));
            pk.w = f2bf(__expf(at[3]));
            *(us4*)&P_lds[mh][nl][tr * 16 + q * 4] = pk;
        }
        // GEMM2: outT[c][n] += sum_m g3[c][m] * P[n][m], G direct from L2
        bf8 pF0 = *(const bf8*)&P_lds[mh][nl][q * 8];
        bf8 pF1 = *(const bf8*)&P_lds[mh][nl][32 + q * 8];
#pragma unroll
        for (int tr = 0; tr < 4; ++tr) {
            const unsigned short* gp = g3b + (size_t)(tr * 16 + l16) * NN + m0;
            bf8 g0 = *(const bf8*)gp;
            bf8 g1 = *(const bf8*)(gp + 32);
            accO[tr] = MFMA(g0, pF0, accO[tr]);
            accO[tr] = MFMA(g1, pF1, accO[tr]);
        }
    }
    // reduce the two m-halves via dedicated LDS
    if (mh == 1) {
#pragma unroll
        for (int tr = 0; tr < 4; ++tr)
#pragma unroll
            for (int r = 0; r < 4; ++r) o_red[tr * 16 + q * 4 + r][nl] = accO[tr][r];
    }
    __syncthreads();
    if (mh == 0) {
#pragma unroll
        for (int tr = 0; tr < 4; ++tr) {
            us4 ov;
            ov.x = f2bf(accO[tr][0] + o_red[tr * 16 + q * 4 + 0][nl]);
            ov.y = f2bf(accO[tr][1] + o_red[tr * 16 + q * 4 + 1][nl]);
            ov.z = f2bf(accO[tr][2] + o_red[tr * 16 + q * 4 + 2][nl]);
            ov.w = f2bf(accO[tr][3] + o_red[tr * 16 + q * 4 + 3][nl]);
            *(us4*)&o_lds[nl][tr * 16 + q * 4] = ov;
        }
    }
    __syncthreads();
    // epilogue: finalT[o][n] = wmask @ outT + x ; o-rows split across halves
    bf8 oB0 = *(const bf8*)&o_lds[nl][q * 8];
    bf8 oB1 = *(const bf8*)&o_lds[nl][32 + q * 8];
#pragma unroll
    for (int t2 = 0; t2 < 2; ++t2) {
        int tr = mh * 2 + t2;
        const unsigned short* wa = wmask_bf + (tr * 16 + l16) * 64 + q * 8;
        bf8 w0 = *(const bf8*)wa;
        bf8 w1 = *(const bf8*)(wa + 32);
        f4 accF = {0.f, 0.f, 0.f, 0.f};
        accF = MFMA(w0, oB0, accF);
        accF = MFMA(w1, oB1, accF);
#pragma unroll
        for (int r = 0; r < 4; ++r) {
            size_t ix = bo + (size_t)(tr * 16 + q * 4 + r) * NN + n0 + nl;
            out[ix] = accF[r] + x[ix];
        }
    }
}

// ---------------------------------------------------------------------------
extern "C" void kernel_launch(void* const* d_in, const int* in_sizes, int n_in,
                              void* d_out, int out_size, void* d_ws, size_t ws_size,
                              hipStream_t stream) {
    const float* x       = (const float*)d_in[0];
    const float* w_phi   = (const float*)d_in[1];
    const float* w_theta = (const float*)d_in[2];
    const float* w_g     = (const float*)d_in[3];
    const float* w_mask  = (const float*)d_in[4];
    const float* w_mv    = (const float*)d_in[5];
    const float* w_mk    = (const float*)d_in[6];
    float* out = (float*)d_out;

    const size_t CN = (size_t)BB * CC * NN;  // 2,097,152 elements
    char* p = (char*)d_ws;
    unsigned short* theta_nc = (unsigned short*)p; p += CN * 2;
    unsigned short* phi_cm = (unsigned short*)p;   p += CN * 2;
    unsigned short* g2_cm = (unsigned short*)p;    p += CN * 2;
    unsigned short* g3_cm = (unsigned short*)p;    p += CN * 2;
    unsigned short* phi2t = (unsigned short*)p;    p += CN * 2;
    unsigned short* wmk_bf = (unsigned short*)p;   p += (size_t)NN * NN * 2;
    unsigned short* wcat_bf = (unsigned short*)p;  p += 192 * 64 * 2;
    unsigned short* wmask_bf = (unsigned short*)p; p += 4096 * 2;

    k0_prep<<<1040, 256, 0, stream>>>(w_mv, w_g, w_theta, w_phi, w_mask, w_mk,
                                      wcat_bf, wmask_bf, wmk_bf);
    k1_channel<<<dim3(16, BB), 256, 0, stream>>>(x, wcat_bf, theta_nc, phi_cm, g2_cm);
    k2_phi2<<<dim3(16, BB), 512, 0, stream>>>(phi_cm, wmk_bf, phi2t);
    k3_stats<<<dim3(16, BB), 512, 0, stream>>>(theta_nc, phi2t, g2_cm, g3_cm);
    k4_out<<<dim3(16, BB), 512, 0, stream>>>(theta_nc, phi2t, g3_cm, wmask_bf, x, out);
}

// Round 2
// 137.300 us; speedup vs baseline: 1.4171x; 1.4171x over previous
//
#include <hip/hip_runtime.h>

#define BB 32
#define CC 64
#define NN 1024

typedef __attribute__((ext_vector_type(8))) short bf8;            // 8 bf16 = 4 VGPR (MFMA A/B frag)
typedef __attribute__((ext_vector_type(4))) float f4;             // MFMA C/D frag
typedef __attribute__((ext_vector_type(4))) unsigned short us4;   // 8B packed bf16 store

__device__ __forceinline__ unsigned short f2bf(float f) {
    unsigned u = __float_as_uint(f);
    return (unsigned short)((u + 0x7fffu + ((u >> 16) & 1u)) >> 16);
}
__device__ __forceinline__ float bf2f(unsigned short u) {
    return __uint_as_float(((unsigned)u) << 16);
}

#define MFMA(a, b, c) __builtin_amdgcn_mfma_f32_16x16x32_bf16(a, b, c, 0, 0, 0)

// Async global->LDS DMA, 16 B per lane: LDS dst = wave-uniform base + lane*16.
#define GLDS(g, l)                                                              \
    __builtin_amdgcn_global_load_lds(                                           \
        (const __attribute__((address_space(1))) void*)(g),                     \
        (__attribute__((address_space(3))) void*)(l), 16, 0, 0)

// XCD-aware swizzle for 512-block grids (8 XCDs, round-robin dispatch):
// each XCD owns 4 contiguous batches (64 blocks) -> per-XCD L2 working set
// ~1.5-2.5 MB < 4 MiB. 512 % 8 == 0 -> bijective.
__device__ __forceinline__ void swz512(int i, int& b, int& t0) {
    int gid = (i & 7) * 64 + (i >> 3);
    b = gid >> 4;
    t0 = (gid & 15) * 64;
}

// ---------------------------------------------------------------------------
// k0: merged prep. Blocks 0-1023: w_mk (1M fp32) -> bf16 (layout unchanged).
// Blocks 1024-1039: wcat_bf[192][64] = stacked bf16 weights (rows 0-63
// w_theta, 64-127 w_phi, 128-191 w_mv@w_g); wmask -> bf16.
// ---------------------------------------------------------------------------
__global__ void k0_prep(const float* __restrict__ w_mv, const float* __restrict__ w_g,
                        const float* __restrict__ w_theta, const float* __restrict__ w_phi,
                        const float* __restrict__ w_mask, const float* __restrict__ w_mk,
                        unsigned short* __restrict__ wcat_bf,
                        unsigned short* __restrict__ wmask_bf,
                        unsigned short* __restrict__ wmk_bf) {
    int tid = threadIdx.x;
    if (blockIdx.x < 1024) {
        int i = (blockIdx.x * 256 + tid) * 4;
        float4 v = *(const float4*)(w_mk + i);
        us4 r;
        r.x = f2bf(v.x); r.y = f2bf(v.y); r.z = f2bf(v.z); r.w = f2bf(v.w);
        *(us4*)(wmk_bf + i) = r;
    } else {
        int idx = (blockIdx.x - 1024) * 256 + tid;
        int d = idx >> 6, e = idx & 63;
        float acc = 0.f;
        for (int c = 0; c < 64; ++c) acc += w_mv[d * 64 + c] * w_g[c * 64 + e];
        wcat_bf[idx] = f2bf(w_theta[idx]);
        wcat_bf[4096 + idx] = f2bf(w_phi[idx]);
        wcat_bf[8192 + idx] = f2bf(acc);
        wmask_bf[idx] = f2bf(w_mask[idx]);
    }
}

// ---------------------------------------------------------------------------
// k1: channel GEMMs via MFMA: out[192][64-tile] = wcat @ x_tile (K=c=64).
// x tile staged transposed+bf16 in LDS (pad 66). theta (rows 0-63) stores
// transposed [n][c] as contiguous us4; phi/g2 store [c][n].
// grid (16, B), 256 thr / 4 waves; wave w -> wcat rows [48w, 48w+48).
// ---------------------------------------------------------------------------
__global__ __launch_bounds__(256, 4) void k1_channel(const float* __restrict__ x,
                                                     const unsigned short* __restrict__ wcat,
                                                     unsigned short* __restrict__ theta_nc,
                                                     unsigned short* __restrict__ phi_cm,
                                                     unsigned short* __restrict__ g2_cm) {
    __shared__ unsigned short xT[64][66];
    int b = blockIdx.y;
    int n0 = blockIdx.x * 64;
    int tid = threadIdx.x;
    int w = tid >> 6, lane = tid & 63, l16 = lane & 15, q = lane >> 4;
    size_t bo = (size_t)b * CC * NN;
#pragma unroll
    for (int i = 0; i < 16; ++i) {
        int idx = i * 256 + tid;
        int c = idx >> 6, n2 = idx & 63;
        xT[n2][c] = f2bf(x[bo + (size_t)c * NN + n0 + n2]);
    }
    __syncthreads();
    // B-frags: lane's n-col = ct*16+l16, k=c contiguous 8 at q*8 (+32)
    bf8 bF[4][2];
#pragma unroll
    for (int ct = 0; ct < 4; ++ct) {
        bF[ct][0] = *(const bf8*)&xT[ct * 16 + l16][q * 8];
        bF[ct][1] = *(const bf8*)&xT[ct * 16 + l16][32 + q * 8];
    }
#pragma unroll
    for (int rt = 0; rt < 3; ++rt) {
        int R = w * 48 + rt * 16;  // wcat row-tile base (16-aligned, within one output)
        const unsigned short* wa = wcat + (R + l16) * 64 + q * 8;
        bf8 a0 = *(const bf8*)wa;
        bf8 a1 = *(const bf8*)(wa + 32);
        int which = R >> 6, rb = R & 63;  // wave-uniform
#pragma unroll
        for (int ct = 0; ct < 4; ++ct) {
            f4 acc = {0.f, 0.f, 0.f, 0.f};
            acc = MFMA(a0, bF[ct][0], acc);
            acc = MFMA(a1, bF[ct][1], acc);
            int n = n0 + ct * 16 + l16;
            if (which == 0) {  // theta: [n][c] layout, rows o contiguous per lane
                us4 t;
                t.x = f2bf(acc[0]); t.y = f2bf(acc[1]);
                t.z = f2bf(acc[2]); t.w = f2bf(acc[3]);
                *(us4*)&theta_nc[bo + (size_t)n * 64 + rb + q * 4] = t;
            } else {
                unsigned short* dst = (which == 1 ? phi_cm : g2_cm) + bo;
#pragma unroll
                for (int r = 0; r < 4; ++r)
                    dst[(size_t)(rb + q * 4 + r) * NN + n] = f2bf(acc[r]);
            }
        }
    }
}

// ---------------------------------------------------------------------------
// k2: phi2t[b][k][c] = sum_m wmk[k][m] * phi_cm[c][m]  (MFMA, K=m=1024)
// 512 thr / 8 waves: (ks = w&3 -> 16 k-rows, mh = w>>2 -> m-half).
// phi tile (shared by the 4 waves of a half) staged via global_load_lds;
// wmk rows (wave-private) loaded direct to regs before the barrier.
// 1D grid, XCD-swizzled: 4 contiguous batches per XCD -> phi L2-local.
// ---------------------------------------------------------------------------
__global__ __launch_bounds__(512, 4) void k2_phi2(const unsigned short* __restrict__ phi_cm,
                                                  const unsigned short* __restrict__ wmk_bf,
                                                  unsigned short* __restrict__ phi2t) {
    __shared__ unsigned short bT[2][4096];  // per-half phi tile [c][m_local] 64x64
    __shared__ float red[64][68];
    int b, k0;
    swz512(blockIdx.x, b, k0);
    int tid = threadIdx.x;
    int w = tid >> 6, lane = tid & 63, l16 = lane & 15, q = lane >> 4;
    int e8 = lane >> 3, c8 = (lane & 7) * 8;
    int ks = w & 3, mh = w >> 2;
    size_t bo = (size_t)b * CC * NN;
    const unsigned short* phib = phi_cm + bo;
    const unsigned short* arow = wmk_bf + (size_t)(k0 + ks * 16 + l16) * NN + q * 8;
    f4 acc[4];
#pragma unroll
    for (int tc = 0; tc < 4; ++tc) acc[tc] = (f4){0.f, 0.f, 0.f, 0.f};

#pragma unroll 1
    for (int mc = 0; mc < 8; ++mc) {
        int m0 = mh * 512 + mc * 64;
        // wave-private A rows: issue before barriers so latency overlaps DMA
        bf8 a0 = *(const bf8*)(arow + m0);
        bf8 a1 = *(const bf8*)(arow + m0 + 32);
        __syncthreads();  // prior readers of bT[mh] done
        const unsigned short* gg = phib + (size_t)(ks * 16 + e8) * NN + m0 + c8;
        GLDS(gg, &bT[mh][ks * 1024]);
        GLDS(gg + (size_t)8 * NN, &bT[mh][ks * 1024 + 512]);
        __syncthreads();  // drains vmcnt: staged tile + a0/a1 ready
#pragma unroll
        for (int tc = 0; tc < 4; ++tc) {
            bf8 b0 = *(const bf8*)&bT[mh][(tc * 16 + l16) * 64 + q * 8];
            bf8 b1 = *(const bf8*)&bT[mh][(tc * 16 + l16) * 64 + 32 + q * 8];
            acc[tc] = MFMA(a0, b0, acc[tc]);
            acc[tc] = MFMA(a1, b1, acc[tc]);
        }
    }
    __syncthreads();
    if (mh == 1) {
#pragma unroll
        for (int tc = 0; tc < 4; ++tc)
#pragma unroll
            for (int r = 0; r < 4; ++r) red[ks * 16 + q * 4 + r][tc * 16 + l16] = acc[tc][r];
    }
    __syncthreads();
    if (mh == 0) {
        unsigned short* prow = phi2t + bo;
#pragma unroll
        for (int tc = 0; tc < 4; ++tc)
#pragma unroll
            for (int r = 0; r < 4; ++r) {
                float v = acc[tc][r] + red[ks * 16 + q * 4 + r][tc * 16 + l16];
                prow[(size_t)(k0 + ks * 16 + q * 4 + r) * 64 + tc * 16 + l16] = f2bf(v);
            }
    }
}

// ---------------------------------------------------------------------------
// k3: S[k] = sum_n exp(att2[n][k]), att2 = theta @ phi2t^T (K=64), then
// g3[c][k] = g2[c][k] / S[k]. 512 thr / 8 waves: (wq -> n offset, nh -> n-half).
// theta rows are wave-private -> register double-buffer prefetch (8 VGPRs).
// No max subtraction: |att2| <~ 45 << 88 (fp32 exp range).
// 1D grid, XCD-swizzled: theta re-reads (16 blocks/batch) become L2-local.
// ---------------------------------------------------------------------------
__global__ __launch_bounds__(512, 4) void k3_stats(const unsigned short* __restrict__ theta_nc,
                                                   const unsigned short* __restrict__ phi2t,
                                                   const unsigned short* __restrict__ g2_cm,
                                                   unsigned short* __restrict__ g3_cm) {
    __shared__ float sred[8][64];
    __shared__ float svs[64];
    int b, k0;
    swz512(blockIdx.x, b, k0);
    int tid = threadIdx.x;
    int w = tid >> 6, lane = tid & 63, l16 = lane & 15, q = lane >> 4;
    int wq = w & 3, nh = w >> 2;
    size_t bo = (size_t)b * CC * NN;
    bf8 bF[4][2];
#pragma unroll
    for (int tc = 0; tc < 4; ++tc)
#pragma unroll
        for (int kc = 0; kc < 2; ++kc)
            bF[tc][kc] = *(const bf8*)(phi2t + bo + (size_t)(k0 + tc * 16 + l16) * 64 + kc * 32 + q * 8);
    float s[4] = {0.f, 0.f, 0.f, 0.f};
    const unsigned short* thb = theta_nc + bo + q * 8;
    int nbase = nh * 8;
    int nrow0 = (nbase + 0) * 64 + wq * 16 + l16;
    bf8 a0 = *(const bf8*)(thb + (size_t)nrow0 * 64);
    bf8 a1 = *(const bf8*)(thb + (size_t)nrow0 * 64 + 32);
    for (int nb = 0; nb < 8; ++nb) {
        bf8 p0, p1;
        if (nb < 7) {  // prefetch next chunk while computing this one
            int nr = (nbase + nb + 1) * 64 + wq * 16 + l16;
            p0 = *(const bf8*)(thb + (size_t)nr * 64);
            p1 = *(const bf8*)(thb + (size_t)nr * 64 + 32);
        }
#pragma unroll
        for (int tc = 0; tc < 4; ++tc) {
            f4 acc = {0.f, 0.f, 0.f, 0.f};
            acc = MFMA(a0, bF[tc][0], acc);
            acc = MFMA(a1, bF[tc][1], acc);
            s[tc] += __expf(acc[0]) + __expf(acc[1]) + __expf(acc[2]) + __expf(acc[3]);
        }
        a0 = p0;
        a1 = p1;
    }
#pragma unroll
    for (int tc = 0; tc < 4; ++tc) {
        s[tc] += __shfl_xor(s[tc], 16, 64);
        s[tc] += __shfl_xor(s[tc], 32, 64);
    }
    if (q == 0) {
#pragma unroll
        for (int tc = 0; tc < 4; ++tc) sred[w][tc * 16 + l16] = s[tc];
    }
    __syncthreads();
    if (tid < 64) {
        float S = 0.f;
#pragma unroll
        for (int ww = 0; ww < 8; ++ww) S += sred[ww][tid];
        svs[tid] = 1.f / S;
    }
    __syncthreads();
    int c0 = tid >> 6, kl = tid & 63;
#pragma unroll
    for (int i = 0; i < 8; ++i) {
        int c = c0 * 8 + i;
        size_t ix = bo + (size_t)c * NN + k0 + kl;
        g3_cm[ix] = f2bf(bf2f(g2_cm[ix]) * svs[kl]);
    }
}

// ---------------------------------------------------------------------------
// k4: per (b, n-tile 64): attT[m][n] = phi2t @ theta^T, P = exp(attT) (Sinv in
// g3), P -> LDS (wave-private rows), outT[c][n] += g3 @ P^T; halves reduce via
// LDS; epilogue finalT = wmask @ outT + x. phi2t/g3 tiles (read identically by
// all 4 n-waves of a half) staged via global_load_lds; theta frags persistent.
// LDS aliasing: o_red over stage, o_lds over P_lds (barrier-separated) ->
// 51.2 KB total. 1D grid, XCD-swizzled (phi2t/g3/theta L2-local per XCD).
// 512 thr / 8 waves: (ws = w&3 -> 16 n's, mh = w>>2 -> m-half).
// ---------------------------------------------------------------------------
__global__ __launch_bounds__(512, 4) void k4_out(const unsigned short* __restrict__ theta_nc,
                                                 const unsigned short* __restrict__ phi2t,
                                                 const unsigned short* __restrict__ g3_cm,
                                                 const unsigned short* __restrict__ wmask_bf,
                                                 const float* __restrict__ x,
                                                 float* __restrict__ out) {
    __shared__ __align__(16) unsigned short smem[25600];  // 51.2 KB
    unsigned short* stage = smem;                               // [16384]: aT/gT tiles
    unsigned short (*P_lds)[64][72] = (unsigned short(*)[64][72])(smem + 16384);  // [2][64][72]
    int b, n0;
    swz512(blockIdx.x, b, n0);
    int tid = threadIdx.x;
    int w = tid >> 6, lane = tid & 63, l16 = lane & 15, q = lane >> 4;
    int e8 = lane >> 3, c8 = (lane & 7) * 8;
    int ws = w & 3, mh = w >> 2;
    int nl = ws * 16 + l16;  // lane's n (LDS row, frag col) — wave-private rows
    size_t bo = (size_t)b * CC * NN;
    unsigned short* aT = stage + mh * 4096;         // phi2t chunk [m_local][c]
    unsigned short* gT = stage + 8192 + mh * 4096;  // g3 chunk [c][m_local]
    bf8 thB[2];
#pragma unroll
    for (int kc = 0; kc < 2; ++kc)
        thB[kc] = *(const bf8*)(theta_nc + bo + (size_t)(n0 + nl) * 64 + kc * 32 + q * 8);
    f4 accO[4];
#pragma unroll
    for (int tr = 0; tr < 4; ++tr) accO[tr] = (f4){0.f, 0.f, 0.f, 0.f};
    const unsigned short* p2b = phi2t + bo;
    const unsigned short* g3b = g3_cm + bo;

#pragma unroll 1
    for (int mc = 0; mc < 8; ++mc) {
        int m0 = mh * 512 + mc * 64;
        __syncthreads();  // prior readers of this half's tiles done
        {
            int r = ws * 16 + e8;
            const unsigned short* ga = p2b + (size_t)(m0 + r) * 64 + c8;
            GLDS(ga, aT + ws * 1024);
            GLDS(ga + 8 * 64, aT + ws * 1024 + 512);
            const unsigned short* gg = g3b + (size_t)r * NN + m0 + c8;
            GLDS(gg, gT + ws * 1024);
            GLDS(gg + (size_t)8 * NN, gT + ws * 1024 + 512);
        }
        __syncthreads();  // drains vmcnt: both tiles staged
        // GEMM1: attT tile (rows m, cols n) ; exp -> P_lds[mh][n][m-local]
#pragma unroll
        for (int tr = 0; tr < 4; ++tr) {
            int row = (tr * 16 + l16) * 64;
            bf8 a0 = *(const bf8*)&aT[row + q * 8];
            bf8 a1 = *(const bf8*)&aT[row + 32 + q * 8];
            f4 at = {0.f, 0.f, 0.f, 0.f};
            at = MFMA(a0, thB[0], at);
            at = MFMA(a1, thB[1], at);
            us4 pk;
            pk.x = f2bf(__expf(at[0]));
            pk.y = f2bf(__expf(at[1]));
            pk.z = f2bf(__expf(at[2]));
            pk.w = f2bf(__expf(at[3]));
            *(us4*)&P_lds[mh][nl][tr * 16 + q * 4] = pk;
        }
        // GEMM2: outT[c][n] += sum_m g3[c][m] * P[n][m]
        bf8 pF0 = *(const bf8*)&P_lds[mh][nl][q * 8];
        bf8 pF1 = *(const bf8*)&P_lds[mh][nl][32 + q * 8];
#pragma unroll
        for (int tr = 0; tr < 4; ++tr) {
            int row = (tr * 16 + l16) * 64;
            bf8 g0 = *(const bf8*)&gT[row + q * 8];
            bf8 g1 = *(const bf8*)&gT[row + 32 + q * 8];
            accO[tr] = MFMA(g0, pF0, accO[tr]);
            accO[tr] = MFMA(g1, pF1, accO[tr]);
        }
    }
    // reduce the two m-halves (o_red aliases stage, o_lds aliases P_lds —
    // all prior readers drained by the barriers below)
    __syncthreads();
    float (*o_red)[68] = (float(*)[68])(void*)stage;            // 64x68 f32 = 17.4 KB
    unsigned short (*o_lds)[72] = (unsigned short(*)[72])(smem + 16384);  // 64x72 bf16
    if (mh == 1) {
#pragma unroll
        for (int tr = 0; tr < 4; ++tr)
#pragma unroll
            for (int r = 0; r < 4; ++r) o_red[tr * 16 + q * 4 + r][nl] = accO[tr][r];
    }
    __syncthreads();
    if (mh == 0) {
#pragma unroll
        for (int tr = 0; tr < 4; ++tr) {
            us4 ov;
            ov.x = f2bf(accO[tr][0] + o_red[tr * 16 + q * 4 + 0][nl]);
            ov.y = f2bf(accO[tr][1] + o_red[tr * 16 + q * 4 + 1][nl]);
            ov.z = f2bf(accO[tr][2] + o_red[tr * 16 + q * 4 + 2][nl]);
            ov.w = f2bf(accO[tr][3] + o_red[tr * 16 + q * 4 + 3][nl]);
            *(us4*)&o_lds[nl][tr * 16 + q * 4] = ov;
        }
    }
    __syncthreads();
    // epilogue: finalT[o][n] = wmask @ outT + x ; o-rows split across halves
    bf8 oB0 = *(const bf8*)&o_lds[nl][q * 8];
    bf8 oB1 = *(const bf8*)&o_lds[nl][32 + q * 8];
#pragma unroll
    for (int t2 = 0; t2 < 2; ++t2) {
        int tr = mh * 2 + t2;
        const unsigned short* wa = wmask_bf + (tr * 16 + l16) * 64 + q * 8;
        bf8 w0 = *(const bf8*)wa;
        bf8 w1 = *(const bf8*)(wa + 32);
        f4 accF = {0.f, 0.f, 0.f, 0.f};
        accF = MFMA(w0, oB0, accF);
        accF = MFMA(w1, oB1, accF);
#pragma unroll
        for (int r = 0; r < 4; ++r) {
            size_t ix = bo + (size_t)(tr * 16 + q * 4 + r) * NN + n0 + nl;
            out[ix] = accF[r] + x[ix];
        }
    }
}

// ---------------------------------------------------------------------------
extern "C" void kernel_launch(void* const* d_in, const int* in_sizes, int n_in,
                              void* d_out, int out_size, void* d_ws, size_t ws_size,
                              hipStream_t stream) {
    const float* x       = (const float*)d_in[0];
    const float* w_phi   = (const float*)d_in[1];
    const float* w_theta = (const float*)d_in[2];
    const float* w_g     = (const float*)d_in[3];
    const float* w_mask  = (const float*)d_in[4];
    const float* w_mv    = (const float*)d_in[5];
    const float* w_mk    = (const float*)d_in[6];
    float* out = (float*)d_out;

    const size_t CN = (size_t)BB * CC * NN;  // 2,097,152 elements
    char* p = (char*)d_ws;
    unsigned short* theta_nc = (unsigned short*)p; p += CN * 2;
    unsigned short* phi_cm = (unsigned short*)p;   p += CN * 2;
    unsigned short* g2_cm = (unsigned short*)p;    p += CN * 2;
    unsigned short* g3_cm = (unsigned short*)p;    p += CN * 2;
    unsigned short* phi2t = (unsigned short*)p;    p += CN * 2;
    unsigned short* wmk_bf = (unsigned short*)p;   p += (size_t)NN * NN * 2;
    unsigned short* wcat_bf = (unsigned short*)p;  p += 192 * 64 * 2;
    unsigned short* wmask_bf = (unsigned short*)p; p += 4096 * 2;

    k0_prep<<<1040, 256, 0, stream>>>(w_mv, w_g, w_theta, w_phi, w_mask, w_mk,
                                      wcat_bf, wmask_bf, wmk_bf);
    k1_channel<<<dim3(16, BB), 256, 0, stream>>>(x, wcat_bf, theta_nc, phi_cm, g2_cm);
    k2_phi2<<<512, 512, 0, stream>>>(phi_cm, wmk_bf, phi2t);
    k3_stats<<<512, 512, 0, stream>>>(theta_nc, phi2t, g2_cm, g3_cm);
    k4_out<<<512, 512, 0, stream>>>(theta_nc, phi2t, g3_cm, wmask_bf, x, out);
}

// Round 3
// 134.901 us; speedup vs baseline: 1.4423x; 1.0178x over previous
//
#include <hip/hip_runtime.h>

#define BB 32
#define CC 64
#define NN 1024

typedef __attribute__((ext_vector_type(8))) short bf8;            // 8 bf16 = 4 VGPR (MFMA A/B frag)
typedef __attribute__((ext_vector_type(4))) float f4;             // MFMA C/D frag
typedef __attribute__((ext_vector_type(4))) unsigned short us4;   // 8B packed bf16 store

__device__ __forceinline__ unsigned short f2bf(float f) {
    unsigned u = __float_as_uint(f);
    return (unsigned short)((u + 0x7fffu + ((u >> 16) & 1u)) >> 16);
}
__device__ __forceinline__ float bf2f(unsigned short u) {
    return __uint_as_float(((unsigned)u) << 16);
}

#define MFMA(a, b, c) __builtin_amdgcn_mfma_f32_16x16x32_bf16(a, b, c, 0, 0, 0)

// Async global->LDS DMA, 16 B per lane: LDS dst = wave-uniform base + lane*16.
#define GLDS(g, l)                                                              \
    __builtin_amdgcn_global_load_lds(                                           \
        (const __attribute__((address_space(1))) void*)(g),                     \
        (__attribute__((address_space(3))) void*)(l), 16, 0, 0)

// XCD-aware swizzle for 512-block grids (8 XCDs, round-robin dispatch):
// each XCD owns 4 contiguous batches (64 blocks). 512 % 8 == 0 -> bijective.
__device__ __forceinline__ void swz512(int i, int& b, int& t0) {
    int gid = (i & 7) * 64 + (i >> 3);
    b = gid >> 4;
    t0 = (gid & 15) * 64;
}

// ---------------------------------------------------------------------------
// k0: merged prep. Blocks 0-1023: w_mk (1M fp32) -> bf16 (layout unchanged).
// Blocks 1024-1039: wcat_bf[192][64] = stacked bf16 weights (rows 0-63
// w_theta, 64-127 w_phi, 128-191 w_mv@w_g); wmask -> bf16.
// ---------------------------------------------------------------------------
__global__ void k0_prep(const float* __restrict__ w_mv, const float* __restrict__ w_g,
                        const float* __restrict__ w_theta, const float* __restrict__ w_phi,
                        const float* __restrict__ w_mask, const float* __restrict__ w_mk,
                        unsigned short* __restrict__ wcat_bf,
                        unsigned short* __restrict__ wmask_bf,
                        unsigned short* __restrict__ wmk_bf) {
    int tid = threadIdx.x;
    if (blockIdx.x < 1024) {
        int i = (blockIdx.x * 256 + tid) * 4;
        float4 v = *(const float4*)(w_mk + i);
        us4 r;
        r.x = f2bf(v.x); r.y = f2bf(v.y); r.z = f2bf(v.z); r.w = f2bf(v.w);
        *(us4*)(wmk_bf + i) = r;
    } else {
        int idx = (blockIdx.x - 1024) * 256 + tid;
        int d = idx >> 6, e = idx & 63;
        float acc = 0.f;
        for (int c = 0; c < 64; ++c) acc += w_mv[d * 64 + c] * w_g[c * 64 + e];
        wcat_bf[idx] = f2bf(w_theta[idx]);
        wcat_bf[4096 + idx] = f2bf(w_phi[idx]);
        wcat_bf[8192 + idx] = f2bf(acc);
        wmask_bf[idx] = f2bf(w_mask[idx]);
    }
}

// ---------------------------------------------------------------------------
// k1: channel GEMMs via MFMA: out[192][64-tile] = wcat @ x_tile (K=c=64).
// x tile staged transposed+bf16 in LDS (pad 66). theta (rows 0-63) stores
// transposed [n][c] as contiguous us4; phi/g2 store [c][n].
// grid (16, B), 256 thr / 4 waves; wave w -> wcat rows [48w, 48w+48).
// ---------------------------------------------------------------------------
__global__ __launch_bounds__(256, 4) void k1_channel(const float* __restrict__ x,
                                                     const unsigned short* __restrict__ wcat,
                                                     unsigned short* __restrict__ theta_nc,
                                                     unsigned short* __restrict__ phi_cm,
                                                     unsigned short* __restrict__ g2_cm) {
    __shared__ unsigned short xT[64][66];
    int b = blockIdx.y;
    int n0 = blockIdx.x * 64;
    int tid = threadIdx.x;
    int w = tid >> 6, lane = tid & 63, l16 = lane & 15, q = lane >> 4;
    size_t bo = (size_t)b * CC * NN;
#pragma unroll
    for (int i = 0; i < 16; ++i) {
        int idx = i * 256 + tid;
        int c = idx >> 6, n2 = idx & 63;
        xT[n2][c] = f2bf(x[bo + (size_t)c * NN + n0 + n2]);
    }
    __syncthreads();
    bf8 bF[4][2];
#pragma unroll
    for (int ct = 0; ct < 4; ++ct) {
        bF[ct][0] = *(const bf8*)&xT[ct * 16 + l16][q * 8];
        bF[ct][1] = *(const bf8*)&xT[ct * 16 + l16][32 + q * 8];
    }
#pragma unroll
    for (int rt = 0; rt < 3; ++rt) {
        int R = w * 48 + rt * 16;  // wcat row-tile base (16-aligned, within one output)
        const unsigned short* wa = wcat + (R + l16) * 64 + q * 8;
        bf8 a0 = *(const bf8*)wa;
        bf8 a1 = *(const bf8*)(wa + 32);
        int which = R >> 6, rb = R & 63;  // wave-uniform
#pragma unroll
        for (int ct = 0; ct < 4; ++ct) {
            f4 acc = {0.f, 0.f, 0.f, 0.f};
            acc = MFMA(a0, bF[ct][0], acc);
            acc = MFMA(a1, bF[ct][1], acc);
            int n = n0 + ct * 16 + l16;
            if (which == 0) {  // theta: [n][c] layout, rows o contiguous per lane
                us4 t;
                t.x = f2bf(acc[0]); t.y = f2bf(acc[1]);
                t.z = f2bf(acc[2]); t.w = f2bf(acc[3]);
                *(us4*)&theta_nc[bo + (size_t)n * 64 + rb + q * 4] = t;
            } else {
                unsigned short* dst = (which == 1 ? phi_cm : g2_cm) + bo;
#pragma unroll
                for (int r = 0; r < 4; ++r)
                    dst[(size_t)(rb + q * 4 + r) * NN + n] = f2bf(acc[r]);
            }
        }
    }
}

// ---------------------------------------------------------------------------
// k2: phi2t[b][k][c] = sum_m wmk[k][m] * phi_cm[c][m]  (MFMA, K=m=1024)
// 512 thr / 8 waves: wave = (ks = w&3 -> 16 k-rows, ch = w>>2 -> 32 c-cols).
// ONE shared 64x64 phi tile per mc (16 chunks), double-buffered, staged via
// global_load_lds with pre-swizzled source cols (XOR row&7 on the 16B col);
// counted s_waitcnt vmcnt(3) keeps next tile's DMA + next A-rows in flight
// across raw s_barriers (T3+T4). No cross-wave reduction (each wave owns its
// output block). A-rows (wmk, wave-private) register-double-buffered.
// ---------------------------------------------------------------------------
__global__ __launch_bounds__(512, 4) void k2_phi2(const unsigned short* __restrict__ phi_cm,
                                                  const unsigned short* __restrict__ wmk_bf,
                                                  unsigned short* __restrict__ phi2t) {
    __shared__ __align__(16) unsigned short bT[2][4096];  // [c=64][m=64] swizzled
    int b, k0;
    swz512(blockIdx.x, b, k0);
    int tid = threadIdx.x;
    int w = tid >> 6, lane = tid & 63, l16 = lane & 15, q = lane >> 4;
    int ks = w & 3, ch = w >> 2;
    size_t bo = (size_t)b * CC * NN;
    int srow = w * 8 + (lane >> 3);                 // c-row this lane stages
    int scol = ((lane & 7) ^ (lane >> 3)) * 8;      // pre-swizzled m-col (shorts)
    const unsigned short* gsrc = phi_cm + bo + (size_t)srow * NN + scol;
    const unsigned short* arow = wmk_bf + (size_t)(k0 + ks * 16 + l16) * NN + q * 8;
    f4 acc[2];
    acc[0] = (f4){0.f, 0.f, 0.f, 0.f};
    acc[1] = (f4){0.f, 0.f, 0.f, 0.f};
    bf8 aC0 = *(const bf8*)(arow);
    bf8 aC1 = *(const bf8*)(arow + 32);
    GLDS(gsrc, &bT[0][w * 512]);
    __syncthreads();  // prologue: drain tile 0 + A rows 0
#pragma unroll 2
    for (int mc = 0; mc < 16; ++mc) {
        const unsigned short* bTc = bT[mc & 1];
        bf8 aN0 = aC0, aN1 = aC1;
        if (mc < 15) {
            int mn = (mc + 1) * 64;
            aN0 = *(const bf8*)(arow + mn);
            aN1 = *(const bf8*)(arow + mn + 32);
            GLDS(gsrc + mn, &bT[(mc + 1) & 1][w * 512]);
            asm volatile("s_waitcnt vmcnt(3)" ::: "memory");  // cur tile + cur A done
        } else {
            asm volatile("s_waitcnt vmcnt(0)" ::: "memory");
        }
        __builtin_amdgcn_s_barrier();
        __builtin_amdgcn_sched_barrier(0);
#pragma unroll
        for (int t = 0; t < 2; ++t) {
            int row = (ch * 2 + t) * 16 + l16;
            int sw = (row & 7) * 8;
            bf8 b0 = *(const bf8*)&bTc[row * 64 + ((q * 8) ^ sw)];
            bf8 b1 = *(const bf8*)&bTc[row * 64 + ((32 + q * 8) ^ sw)];
            acc[t] = MFMA(aC0, b0, acc[t]);
            acc[t] = MFMA(aC1, b1, acc[t]);
        }
        __builtin_amdgcn_s_barrier();  // all readers done -> next overwrite safe
        __builtin_amdgcn_sched_barrier(0);
        aC0 = aN0;
        aC1 = aN1;
    }
    unsigned short* prow = phi2t + bo;
#pragma unroll
    for (int t = 0; t < 2; ++t) {
        int ccol = (ch * 2 + t) * 16 + l16;
#pragma unroll
        for (int r = 0; r < 4; ++r)
            prow[(size_t)(k0 + ks * 16 + q * 4 + r) * 64 + ccol] = f2bf(acc[t][r]);
    }
}

// ---------------------------------------------------------------------------
// k3: S[k] = sum_n exp(att2[n][k]), att2 = theta @ phi2t^T (K=64); writes
// sinv[b][k] = 1/S only (g-scaling folded into k4's P). 512 thr / 8 waves.
// theta rows wave-private -> register double-buffer prefetch.
// No max subtraction: |att2| <~ 45 << 88 (fp32 exp range).
// ---------------------------------------------------------------------------
__global__ __launch_bounds__(512, 4) void k3_stats(const unsigned short* __restrict__ theta_nc,
                                                   const unsigned short* __restrict__ phi2t,
                                                   float* __restrict__ sinv) {
    __shared__ float sred[8][64];
    int b, k0;
    swz512(blockIdx.x, b, k0);
    int tid = threadIdx.x;
    int w = tid >> 6, lane = tid & 63, l16 = lane & 15, q = lane >> 4;
    int wq = w & 3, nh = w >> 2;
    size_t bo = (size_t)b * CC * NN;
    bf8 bF[4][2];
#pragma unroll
    for (int tc = 0; tc < 4; ++tc)
#pragma unroll
        for (int kc = 0; kc < 2; ++kc)
            bF[tc][kc] = *(const bf8*)(phi2t + bo + (size_t)(k0 + tc * 16 + l16) * 64 + kc * 32 + q * 8);
    float s[4] = {0.f, 0.f, 0.f, 0.f};
    const unsigned short* thb = theta_nc + bo + q * 8;
    int nbase = nh * 8;
    int nrow0 = (nbase + 0) * 64 + wq * 16 + l16;
    bf8 a0 = *(const bf8*)(thb + (size_t)nrow0 * 64);
    bf8 a1 = *(const bf8*)(thb + (size_t)nrow0 * 64 + 32);
    for (int nb = 0; nb < 8; ++nb) {
        bf8 p0, p1;
        if (nb < 7) {  // prefetch next chunk while computing this one
            int nr = (nbase + nb + 1) * 64 + wq * 16 + l16;
            p0 = *(const bf8*)(thb + (size_t)nr * 64);
            p1 = *(const bf8*)(thb + (size_t)nr * 64 + 32);
        }
#pragma unroll
        for (int tc = 0; tc < 4; ++tc) {
            f4 acc = {0.f, 0.f, 0.f, 0.f};
            acc = MFMA(a0, bF[tc][0], acc);
            acc = MFMA(a1, bF[tc][1], acc);
            s[tc] += __expf(acc[0]) + __expf(acc[1]) + __expf(acc[2]) + __expf(acc[3]);
        }
        a0 = p0;
        a1 = p1;
    }
#pragma unroll
    for (int tc = 0; tc < 4; ++tc) {
        s[tc] += __shfl_xor(s[tc], 16, 64);
        s[tc] += __shfl_xor(s[tc], 32, 64);
    }
    if (q == 0) {
#pragma unroll
        for (int tc = 0; tc < 4; ++tc) sred[w][tc * 16 + l16] = s[tc];
    }
    __syncthreads();
    if (tid < 64) {
        float S = 0.f;
#pragma unroll
        for (int ww = 0; ww < 8; ++ww) S += sred[ww][tid];
        sinv[(size_t)b * NN + k0 + tid] = 1.f / S;
    }
}

// ---------------------------------------------------------------------------
// k4: per (b, n-tile 64): attT[m][n] = phi2t @ theta^T, P' = exp(attT)*Sinv[m]
// (softmax folded here), outT[c][n] += g2 @ P'^T over 16 m-chunks; epilogue
// finalT = wmask @ outT + x. ONE shared (aT,gT) 64x64 pair per chunk,
// double-buffered, source-swizzled global_load_lds + counted vmcnt(2) across
// raw barriers (T3+T4). Waves: (ws = w&3 -> 16 n's, ph = w>>2 -> m/k-half of
// each chunk); P rows wave-private per (ws,ph); ph-partials reduced at end.
// LDS 45 KB: buf0 aT/gT | buf1 aT/gT | P[64][72] | svs[1024]f32.
// ---------------------------------------------------------------------------
__global__ __launch_bounds__(512, 4) void k4_out(const unsigned short* __restrict__ theta_nc,
                                                 const unsigned short* __restrict__ phi2t,
                                                 const unsigned short* __restrict__ g2_cm,
                                                 const float* __restrict__ sinv,
                                                 const unsigned short* __restrict__ wmask_bf,
                                                 const float* __restrict__ x,
                                                 float* __restrict__ out) {
    __shared__ __align__(16) unsigned short smem[23040];  // 46080 B
    float* svs_l = (float*)(smem + 20992);                // 1024 f32
    int b, n0;
    swz512(blockIdx.x, b, n0);
    int tid = threadIdx.x;
    int w = tid >> 6, lane = tid & 63, l16 = lane & 15, q = lane >> 4;
    int ws = w & 3, ph = w >> 2;
    int nl = ws * 16 + l16;  // lane's n (frag col); P rows wave-private
    size_t bo = (size_t)b * CC * NN;
    int srow = w * 8 + (lane >> 3);             // staged row (m for aT, c for gT)
    int scol = ((lane & 7) ^ (lane >> 3)) * 8;  // pre-swizzled col (shorts)
    const unsigned short* p2b = phi2t + bo;
    const unsigned short* g2b = g2_cm + bo;
    if (tid < 256) *(f4*)&svs_l[tid * 4] = *(const f4*)(sinv + (size_t)b * NN + tid * 4);
    bf8 thB[2];
#pragma unroll
    for (int kc = 0; kc < 2; ++kc)
        thB[kc] = *(const bf8*)(theta_nc + bo + (size_t)(n0 + nl) * 64 + kc * 32 + q * 8);
    f4 accO[4];
#pragma unroll
    for (int ct = 0; ct < 4; ++ct) accO[ct] = (f4){0.f, 0.f, 0.f, 0.f};
    // prologue: stage chunk 0 into buf 0
    GLDS(p2b + (size_t)srow * 64 + scol, smem + w * 512);
    GLDS(g2b + (size_t)srow * NN + scol, smem + 4096 + w * 512);
    __syncthreads();  // drains prologue DMA + svs/thB loads
#pragma unroll 2
    for (int mc = 0; mc < 16; ++mc) {
        unsigned short* aT = smem + (mc & 1) * 8192;  // phi2t chunk [m64][c64]
        unsigned short* gT = aT + 4096;               // g2 chunk [c64][m64]
        if (mc < 15) {
            int mn = (mc + 1) * 64;
            unsigned short* aN = smem + ((mc + 1) & 1) * 8192;
            GLDS(p2b + (size_t)(mn + srow) * 64 + scol, aN + w * 512);
            GLDS(g2b + (size_t)srow * NN + mn + scol, aN + 4096 + w * 512);
            asm volatile("s_waitcnt vmcnt(2)" ::: "memory");  // cur chunk staged
        } else {
            asm volatile("s_waitcnt vmcnt(0)" ::: "memory");
        }
        __builtin_amdgcn_s_barrier();
        __builtin_amdgcn_sched_barrier(0);
        int m0 = mc * 64;
        unsigned short* Pr = smem + 16384 + nl * 72 + ph * 32;
        int swz = (l16 & 7) * 8;
        // GEMM1: att rows (ph-half of chunk) x 16 n-cols; P' = exp * Sinv
#pragma unroll
        for (int mrr = 0; mrr < 2; ++mrr) {
            int rowA = ph * 32 + mrr * 16 + l16;
            bf8 a0 = *(const bf8*)&aT[rowA * 64 + ((q * 8) ^ swz)];
            bf8 a1 = *(const bf8*)&aT[rowA * 64 + ((32 + q * 8) ^ swz)];
            f4 at = {0.f, 0.f, 0.f, 0.f};
            at = MFMA(a0, thB[0], at);
            at = MFMA(a1, thB[1], at);
            f4 sv = *(const f4*)&svs_l[m0 + ph * 32 + mrr * 16 + q * 4];
            us4 pk;
            pk.x = f2bf(__expf(at[0]) * sv[0]);
            pk.y = f2bf(__expf(at[1]) * sv[1]);
            pk.z = f2bf(__expf(at[2]) * sv[2]);
            pk.w = f2bf(__expf(at[3]) * sv[3]);
            *(us4*)&Pr[mrr * 16 + q * 4] = pk;
        }
        // GEMM2: outT[c][n] += g2[c][k in ph-half] * P'[n][k]  (K=32, 1 MFMA/ct)
        bf8 pF = *(const bf8*)&Pr[q * 8];
#pragma unroll
        for (int ct = 0; ct < 4; ++ct) {
            int rowG = ct * 16 + l16;
            bf8 g0 = *(const bf8*)&gT[rowG * 64 + (((ph * 32) + q * 8) ^ swz)];
            accO[ct] = MFMA(g0, pF, accO[ct]);
        }
        __builtin_amdgcn_s_barrier();  // readers done -> next overwrite safe
        __builtin_amdgcn_sched_barrier(0);
    }
    // ph-pair reduction (o_red aliases buf region; o_lds after it)
    float* o_red = (float*)smem;                 // [64][68] f32 = 17408 B
    unsigned short* o_lds = smem + 8704;         // [64][72] bf16
    if (ph == 1) {
#pragma unroll
        for (int ct = 0; ct < 4; ++ct)
#pragma unroll
            for (int r = 0; r < 4; ++r) o_red[(ct * 16 + q * 4 + r) * 68 + nl] = accO[ct][r];
    }
    __syncthreads();
    if (ph == 0) {
#pragma unroll
        for (int ct = 0; ct < 4; ++ct) {
            us4 ov;
            ov.x = f2bf(accO[ct][0] + o_red[(ct * 16 + q * 4 + 0) * 68 + nl]);
            ov.y = f2bf(accO[ct][1] + o_red[(ct * 16 + q * 4 + 1) * 68 + nl]);
            ov.z = f2bf(accO[ct][2] + o_red[(ct * 16 + q * 4 + 2) * 68 + nl]);
            ov.w = f2bf(accO[ct][3] + o_red[(ct * 16 + q * 4 + 3) * 68 + nl]);
            *(us4*)&o_lds[nl * 72 + ct * 16 + q * 4] = ov;
        }
    }
    __syncthreads();
    // epilogue: finalT[o][n] = wmask @ outT + x ; o-rows split across ph
    bf8 oB0 = *(const bf8*)&o_lds[nl * 72 + q * 8];
    bf8 oB1 = *(const bf8*)&o_lds[nl * 72 + 32 + q * 8];
#pragma unroll
    for (int t2 = 0; t2 < 2; ++t2) {
        int tr = ph * 2 + t2;
        const unsigned short* wa = wmask_bf + (tr * 16 + l16) * 64 + q * 8;
        bf8 w0 = *(const bf8*)wa;
        bf8 w1 = *(const bf8*)(wa + 32);
        f4 accF = {0.f, 0.f, 0.f, 0.f};
        accF = MFMA(w0, oB0, accF);
        accF = MFMA(w1, oB1, accF);
#pragma unroll
        for (int r = 0; r < 4; ++r) {
            size_t ix = bo + (size_t)(tr * 16 + q * 4 + r) * NN + n0 + nl;
            out[ix] = accF[r] + x[ix];
        }
    }
}

// ---------------------------------------------------------------------------
extern "C" void kernel_launch(void* const* d_in, const int* in_sizes, int n_in,
                              void* d_out, int out_size, void* d_ws, size_t ws_size,
                              hipStream_t stream) {
    const float* x       = (const float*)d_in[0];
    const float* w_phi   = (const float*)d_in[1];
    const float* w_theta = (const float*)d_in[2];
    const float* w_g     = (const float*)d_in[3];
    const float* w_mask  = (const float*)d_in[4];
    const float* w_mv    = (const float*)d_in[5];
    const float* w_mk    = (const float*)d_in[6];
    float* out = (float*)d_out;

    const size_t CN = (size_t)BB * CC * NN;  // 2,097,152 elements
    char* p = (char*)d_ws;
    unsigned short* theta_nc = (unsigned short*)p; p += CN * 2;
    unsigned short* phi_cm = (unsigned short*)p;   p += CN * 2;
    unsigned short* g2_cm = (unsigned short*)p;    p += CN * 2;
    float* sinv = (float*)p;                       p += CN * 2;  // uses 128 KB of slot
    unsigned short* phi2t = (unsigned short*)p;    p += CN * 2;
    unsigned short* wmk_bf = (unsigned short*)p;   p += (size_t)NN * NN * 2;
    unsigned short* wcat_bf = (unsigned short*)p;  p += 192 * 64 * 2;
    unsigned short* wmask_bf = (unsigned short*)p; p += 4096 * 2;

    k0_prep<<<1040, 256, 0, stream>>>(w_mv, w_g, w_theta, w_phi, w_mask, w_mk,
                                      wcat_bf, wmask_bf, wmk_bf);
    k1_channel<<<dim3(16, BB), 256, 0, stream>>>(x, wcat_bf, theta_nc, phi_cm, g2_cm);
    k2_phi2<<<512, 512, 0, stream>>>(phi_cm, wmk_bf, phi2t);
    k3_stats<<<512, 512, 0, stream>>>(theta_nc, phi2t, sinv);
    k4_out<<<512, 512, 0, stream>>>(theta_nc, phi2t, g2_cm, sinv, wmask_bf, x, out);
}

// Round 4
// 131.662 us; speedup vs baseline: 1.4778x; 1.0246x over previous
//
#include <hip/hip_runtime.h>

#define BB 32
#define CC 64
#define NN 1024

typedef __attribute__((ext_vector_type(8))) short bf8;            // 8 bf16 = 4 VGPR (MFMA A/B frag)
typedef __attribute__((ext_vector_type(4))) float f4;             // MFMA C/D frag
typedef __attribute__((ext_vector_type(4))) unsigned short us4;   // 8B packed bf16 store

__device__ __forceinline__ unsigned short f2bf(float f) {
    unsigned u = __float_as_uint(f);
    return (unsigned short)((u + 0x7fffu + ((u >> 16) & 1u)) >> 16);
}
__device__ __forceinline__ float bf2f(unsigned short u) {
    return __uint_as_float(((unsigned)u) << 16);
}

#define MFMA(a, b, c) __builtin_amdgcn_mfma_f32_16x16x32_bf16(a, b, c, 0, 0, 0)

// Async global->LDS DMA, 16 B per lane: LDS dst = wave-uniform base + lane*16.
#define GLDS(g, l)                                                              \
    __builtin_amdgcn_global_load_lds(                                           \
        (const __attribute__((address_space(1))) void*)(g),                     \
        (__attribute__((address_space(3))) void*)(l), 16, 0, 0)

// XCD-aware swizzle for 512-block grids (8 XCDs, round-robin dispatch):
// each XCD owns 4 contiguous batches (64 blocks). 512 % 8 == 0 -> bijective.
__device__ __forceinline__ void swz512(int i, int& b, int& t0) {
    int gid = (i & 7) * 64 + (i >> 3);
    b = gid >> 4;
    t0 = (gid & 15) * 64;
}

// ---------------------------------------------------------------------------
// k0: merged prep. Blocks 0-1023: w_mk (1M fp32) -> bf16 (layout unchanged).
// Blocks 1024-1039: wcat_bf[192][64] = stacked bf16 weights (rows 0-63
// w_theta, 64-127 w_phi, 128-191 w_mv@w_g); wmask -> bf16.
// ---------------------------------------------------------------------------
__global__ void k0_prep(const float* __restrict__ w_mv, const float* __restrict__ w_g,
                        const float* __restrict__ w_theta, const float* __restrict__ w_phi,
                        const float* __restrict__ w_mask, const float* __restrict__ w_mk,
                        unsigned short* __restrict__ wcat_bf,
                        unsigned short* __restrict__ wmask_bf,
                        unsigned short* __restrict__ wmk_bf) {
    int tid = threadIdx.x;
    if (blockIdx.x < 1024) {
        int i = (blockIdx.x * 256 + tid) * 4;
        float4 v = *(const float4*)(w_mk + i);
        us4 r;
        r.x = f2bf(v.x); r.y = f2bf(v.y); r.z = f2bf(v.z); r.w = f2bf(v.w);
        *(us4*)(wmk_bf + i) = r;
    } else {
        int idx = (blockIdx.x - 1024) * 256 + tid;
        int d = idx >> 6, e = idx & 63;
        float acc = 0.f;
        for (int c = 0; c < 64; ++c) acc += w_mv[d * 64 + c] * w_g[c * 64 + e];
        wcat_bf[idx] = f2bf(w_theta[idx]);
        wcat_bf[4096 + idx] = f2bf(w_phi[idx]);
        wcat_bf[8192 + idx] = f2bf(acc);
        wmask_bf[idx] = f2bf(w_mask[idx]);
    }
}

// ---------------------------------------------------------------------------
// k1: channel GEMMs via MFMA: out[192][32-tile] = wcat @ x_tile (K=c=64).
// 32-n tiles -> grid (32,B) = 1024 blocks (4 blk/CU, 16 waves/CU; was 8).
// x staged via float4 (16B/lane coalesced) + f2bf -> xT[n][c] (pad 72 keeps
// 16B row alignment; bank rotation 4/row). theta stores [n][c] us4;
// phi/g2 store [c][n]. 256 thr / 4 waves; wave w -> wcat rows [48w,48w+48).
// ---------------------------------------------------------------------------
__global__ __launch_bounds__(256, 4) void k1_channel(const float* __restrict__ x,
                                                     const unsigned short* __restrict__ wcat,
                                                     unsigned short* __restrict__ theta_nc,
                                                     unsigned short* __restrict__ phi_cm,
                                                     unsigned short* __restrict__ g2_cm) {
    __shared__ __align__(16) unsigned short xT[32][72];
    int b = blockIdx.y;
    int n0 = blockIdx.x * 32;
    int tid = threadIdx.x;
    int w = tid >> 6, lane = tid & 63, l16 = lane & 15, q = lane >> 4;
    size_t bo = (size_t)b * CC * NN;
#pragma unroll
    for (int i = 0; i < 2; ++i) {
        int f = i * 1024 + tid * 4;
        int c = f >> 5, n = f & 31;
        float4 v = *(const float4*)(x + bo + (size_t)c * NN + n0 + n);
        xT[n + 0][c] = f2bf(v.x);
        xT[n + 1][c] = f2bf(v.y);
        xT[n + 2][c] = f2bf(v.z);
        xT[n + 3][c] = f2bf(v.w);
    }
    __syncthreads();
    bf8 bF[2][2];
#pragma unroll
    for (int ct = 0; ct < 2; ++ct) {
        bF[ct][0] = *(const bf8*)&xT[ct * 16 + l16][q * 8];
        bF[ct][1] = *(const bf8*)&xT[ct * 16 + l16][32 + q * 8];
    }
#pragma unroll
    for (int rt = 0; rt < 3; ++rt) {
        int R = w * 48 + rt * 16;  // wcat row-tile base (16-aligned, within one output)
        const unsigned short* wa = wcat + (R + l16) * 64 + q * 8;
        bf8 a0 = *(const bf8*)wa;
        bf8 a1 = *(const bf8*)(wa + 32);
        int which = R >> 6, rb = R & 63;  // wave-uniform
#pragma unroll
        for (int ct = 0; ct < 2; ++ct) {
            f4 acc = {0.f, 0.f, 0.f, 0.f};
            acc = MFMA(a0, bF[ct][0], acc);
            acc = MFMA(a1, bF[ct][1], acc);
            int n = n0 + ct * 16 + l16;
            if (which == 0) {  // theta: [n][c] layout, rows o contiguous per lane
                us4 t;
                t.x = f2bf(acc[0]); t.y = f2bf(acc[1]);
                t.z = f2bf(acc[2]); t.w = f2bf(acc[3]);
                *(us4*)&theta_nc[bo + (size_t)n * 64 + rb + q * 4] = t;
            } else {
                unsigned short* dst = (which == 1 ? phi_cm : g2_cm) + bo;
#pragma unroll
                for (int r = 0; r < 4; ++r)
                    dst[(size_t)(rb + q * 4 + r) * NN + n] = f2bf(acc[r]);
            }
        }
    }
}

// ---------------------------------------------------------------------------
// k23: fused k2+k3. Phase A (= old k2): phi2t tile [64k][64c] = wmk @ phi^T
// via double-buffered GLDS pipeline (counted vmcnt(3), XOR-swizzled tiles);
// result written to global phi2t AND kept in LDS pT. Phase B (= old k3):
// S[k] = sum_n exp(theta[n] . phi2t[k]); theta rows (128B contiguous) staged
// in 64-row chunks via ONE coalesced GLDS per wave per chunk, double-buffered
// with counted vmcnt(1) — replaces old k3's 128B-strided 64-line loads.
// phi2t B-frags read from pT (LDS, zero global re-read). Writes sinv = 1/S.
// 512 thr / 8 waves. LDS ~26 KB.
// ---------------------------------------------------------------------------
__global__ __launch_bounds__(512, 4) void k23_phi2_stats(
    const unsigned short* __restrict__ phi_cm,
    const unsigned short* __restrict__ wmk_bf,
    const unsigned short* __restrict__ theta_nc,
    unsigned short* __restrict__ phi2t,
    float* __restrict__ sinv) {
    __shared__ __align__(16) unsigned short bT[2][4096];  // phase A: phi tiles / phase B: theta chunks
    __shared__ __align__(16) unsigned short pT[64][72];   // phi2t tile [k][c], pad 72
    __shared__ float sred[8][32];
    int b, k0;
    swz512(blockIdx.x, b, k0);
    int tid = threadIdx.x;
    int w = tid >> 6, lane = tid & 63, l16 = lane & 15, q = lane >> 4;
    size_t bo = (size_t)b * CC * NN;
    int srow = w * 8 + (lane >> 3);                 // staged row (linear LDS dest)
    int scol = ((lane & 7) ^ (lane >> 3)) * 8;      // pre-swizzled source col (shorts)

    // ================= phase A: phi2t tile =================
    int ks = w & 3, ch = w >> 2;
    const unsigned short* gsrc = phi_cm + bo + (size_t)srow * NN + scol;
    const unsigned short* arow = wmk_bf + (size_t)(k0 + ks * 16 + l16) * NN + q * 8;
    f4 acc[2];
    acc[0] = (f4){0.f, 0.f, 0.f, 0.f};
    acc[1] = (f4){0.f, 0.f, 0.f, 0.f};
    bf8 aC0 = *(const bf8*)(arow);
    bf8 aC1 = *(const bf8*)(arow + 32);
    GLDS(gsrc, &bT[0][w * 512]);
    __syncthreads();  // prologue: tile 0 + A rows 0 ready
#pragma unroll 2
    for (int mc = 0; mc < 16; ++mc) {
        const unsigned short* bTc = bT[mc & 1];
        bf8 aN0 = aC0, aN1 = aC1;
        if (mc < 15) {
            int mn = (mc + 1) * 64;
            aN0 = *(const bf8*)(arow + mn);
            aN1 = *(const bf8*)(arow + mn + 32);
            GLDS(gsrc + mn, &bT[(mc + 1) & 1][w * 512]);
            asm volatile("s_waitcnt vmcnt(3)" ::: "memory");  // cur tile + cur A done
        } else {
            asm volatile("s_waitcnt vmcnt(0)" ::: "memory");
        }
        __builtin_amdgcn_s_barrier();
        __builtin_amdgcn_sched_barrier(0);
#pragma unroll
        for (int t = 0; t < 2; ++t) {
            int row = (ch * 2 + t) * 16 + l16;
            int sw = (row & 7) * 8;
            bf8 b0 = *(const bf8*)&bTc[row * 64 + ((q * 8) ^ sw)];
            bf8 b1 = *(const bf8*)&bTc[row * 64 + ((32 + q * 8) ^ sw)];
            acc[t] = MFMA(aC0, b0, acc[t]);
            acc[t] = MFMA(aC1, b1, acc[t]);
        }
        __builtin_amdgcn_s_barrier();  // all readers done -> next overwrite safe
        __builtin_amdgcn_sched_barrier(0);
        aC0 = aN0;
        aC1 = aN1;
    }
    // epilogue A: tile -> pT (LDS) + phi2t (global, needed by k4)
    unsigned short* prow = phi2t + bo;
#pragma unroll
    for (int t = 0; t < 2; ++t) {
        int ccol = (ch * 2 + t) * 16 + l16;
#pragma unroll
        for (int r = 0; r < 4; ++r) {
            int krow = ks * 16 + q * 4 + r;
            unsigned short v = f2bf(acc[t][r]);
            pT[krow][ccol] = v;
            prow[(size_t)(k0 + krow) * 64 + ccol] = v;
        }
    }

    // ================= phase B: S[k] over all n =================
    int rg = w & 3, th = w >> 2;
    const unsigned short* thsrc = theta_nc + bo + (size_t)srow * 64 + scol;
    GLDS(thsrc, &bT[0][w * 512]);  // theta chunk 0 (overlaps pT write drain)
    __syncthreads();               // drains pT ds_writes + chunk-0 DMA
    bf8 pF[2][2];
#pragma unroll
    for (int t = 0; t < 2; ++t)
#pragma unroll
        for (int kc = 0; kc < 2; ++kc)
            pF[t][kc] = *(const bf8*)&pT[(th * 2 + t) * 16 + l16][kc * 32 + q * 8];
    float s[2] = {0.f, 0.f};
#pragma unroll 2
    for (int nc = 0; nc < 16; ++nc) {
        const unsigned short* tTc = bT[nc & 1];
        if (nc < 15) {
            GLDS(thsrc + (nc + 1) * 4096, &bT[(nc + 1) & 1][w * 512]);
            asm volatile("s_waitcnt vmcnt(1)" ::: "memory");  // cur chunk staged
        } else {
            asm volatile("s_waitcnt vmcnt(0)" ::: "memory");
        }
        __builtin_amdgcn_s_barrier();
        __builtin_amdgcn_sched_barrier(0);
        int r = rg * 16 + l16;
        int sw = (r & 7);
        bf8 a0 = *(const bf8*)&tTc[r * 64 + ((q ^ sw) * 8)];
        bf8 a1 = *(const bf8*)&tTc[r * 64 + (((4 + q) ^ sw) * 8)];
#pragma unroll
        for (int t = 0; t < 2; ++t) {
            f4 at = {0.f, 0.f, 0.f, 0.f};
            at = MFMA(a0, pF[t][0], at);
            at = MFMA(a1, pF[t][1], at);
            s[t] += __expf(at[0]) + __expf(at[1]) + __expf(at[2]) + __expf(at[3]);
        }
        __builtin_amdgcn_s_barrier();  // readers done -> next overwrite safe
        __builtin_amdgcn_sched_barrier(0);
    }
#pragma unroll
    for (int t = 0; t < 2; ++t) {
        s[t] += __shfl_xor(s[t], 16, 64);
        s[t] += __shfl_xor(s[t], 32, 64);
    }
    if (q == 0) {
        sred[w][l16] = s[0];
        sred[w][16 + l16] = s[1];
    }
    __syncthreads();
    if (tid < 64) {
        int th2 = tid >> 5, rem = tid & 31;
        float S = sred[th2 * 4 + 0][rem] + sred[th2 * 4 + 1][rem] +
                  sred[th2 * 4 + 2][rem] + sred[th2 * 4 + 3][rem];
        sinv[(size_t)b * NN + k0 + tid] = 1.f / S;
    }
}

// ---------------------------------------------------------------------------
// k4: per (b, n-tile 64): attT[m][n] = phi2t @ theta^T, P' = exp(attT)*Sinv[m]
// (softmax folded here), outT[c][n] += g2 @ P'^T over 16 m-chunks; epilogue
// finalT = wmask @ outT + x. ONE shared (aT,gT) 64x64 pair per chunk,
// double-buffered, source-swizzled global_load_lds + counted vmcnt(2) across
// raw barriers (T3+T4). Waves: (ws = w&3 -> 16 n's, ph = w>>2 -> m/k-half of
// each chunk); P rows wave-private per (ws,ph); ph-partials reduced at end.
// LDS 45 KB: buf0 aT/gT | buf1 aT/gT | P[64][72] | svs[1024]f32.
// ---------------------------------------------------------------------------
__global__ __launch_bounds__(512, 4) void k4_out(const unsigned short* __restrict__ theta_nc,
                                                 const unsigned short* __restrict__ phi2t,
                                                 const unsigned short* __restrict__ g2_cm,
                                                 const float* __restrict__ sinv,
                                                 const unsigned short* __restrict__ wmask_bf,
                                                 const float* __restrict__ x,
                                                 float* __restrict__ out) {
    __shared__ __align__(16) unsigned short smem[23040];  // 46080 B
    float* svs_l = (float*)(smem + 20992);                // 1024 f32
    int b, n0;
    swz512(blockIdx.x, b, n0);
    int tid = threadIdx.x;
    int w = tid >> 6, lane = tid & 63, l16 = lane & 15, q = lane >> 4;
    int ws = w & 3, ph = w >> 2;
    int nl = ws * 16 + l16;  // lane's n (frag col); P rows wave-private
    size_t bo = (size_t)b * CC * NN;
    int srow = w * 8 + (lane >> 3);             // staged row (m for aT, c for gT)
    int scol = ((lane & 7) ^ (lane >> 3)) * 8;  // pre-swizzled col (shorts)
    const unsigned short* p2b = phi2t + bo;
    const unsigned short* g2b = g2_cm + bo;
    if (tid < 256) *(f4*)&svs_l[tid * 4] = *(const f4*)(sinv + (size_t)b * NN + tid * 4);
    bf8 thB[2];
#pragma unroll
    for (int kc = 0; kc < 2; ++kc)
        thB[kc] = *(const bf8*)(theta_nc + bo + (size_t)(n0 + nl) * 64 + kc * 32 + q * 8);
    f4 accO[4];
#pragma unroll
    for (int ct = 0; ct < 4; ++ct) accO[ct] = (f4){0.f, 0.f, 0.f, 0.f};
    // prologue: stage chunk 0 into buf 0
    GLDS(p2b + (size_t)srow * 64 + scol, smem + w * 512);
    GLDS(g2b + (size_t)srow * NN + scol, smem + 4096 + w * 512);
    __syncthreads();  // drains prologue DMA + svs/thB loads
#pragma unroll 2
    for (int mc = 0; mc < 16; ++mc) {
        unsigned short* aT = smem + (mc & 1) * 8192;  // phi2t chunk [m64][c64]
        unsigned short* gT = aT + 4096;               // g2 chunk [c64][m64]
        if (mc < 15) {
            int mn = (mc + 1) * 64;
            unsigned short* aN = smem + ((mc + 1) & 1) * 8192;
            GLDS(p2b + (size_t)(mn + srow) * 64 + scol, aN + w * 512);
            GLDS(g2b + (size_t)srow * NN + mn + scol, aN + 4096 + w * 512);
            asm volatile("s_waitcnt vmcnt(2)" ::: "memory");  // cur chunk staged
        } else {
            asm volatile("s_waitcnt vmcnt(0)" ::: "memory");
        }
        __builtin_amdgcn_s_barrier();
        __builtin_amdgcn_sched_barrier(0);
        int m0 = mc * 64;
        unsigned short* Pr = smem + 16384 + nl * 72 + ph * 32;
        int swz = (l16 & 7) * 8;
        // GEMM1: att rows (ph-half of chunk) x 16 n-cols; P' = exp * Sinv
#pragma unroll
        for (int mrr = 0; mrr < 2; ++mrr) {
            int rowA = ph * 32 + mrr * 16 + l16;
            bf8 a0 = *(const bf8*)&aT[rowA * 64 + ((q * 8) ^ swz)];
            bf8 a1 = *(const bf8*)&aT[rowA * 64 + ((32 + q * 8) ^ swz)];
            f4 at = {0.f, 0.f, 0.f, 0.f};
            at = MFMA(a0, thB[0], at);
            at = MFMA(a1, thB[1], at);
            f4 sv = *(const f4*)&svs_l[m0 + ph * 32 + mrr * 16 + q * 4];
            us4 pk;
            pk.x = f2bf(__expf(at[0]) * sv[0]);
            pk.y = f2bf(__expf(at[1]) * sv[1]);
            pk.z = f2bf(__expf(at[2]) * sv[2]);
            pk.w = f2bf(__expf(at[3]) * sv[3]);
            *(us4*)&Pr[mrr * 16 + q * 4] = pk;
        }
        // GEMM2: outT[c][n] += g2[c][k in ph-half] * P'[n][k]  (K=32, 1 MFMA/ct)
        bf8 pF = *(const bf8*)&Pr[q * 8];
#pragma unroll
        for (int ct = 0; ct < 4; ++ct) {
            int rowG = ct * 16 + l16;
            bf8 g0 = *(const bf8*)&gT[rowG * 64 + (((ph * 32) + q * 8) ^ swz)];
            accO[ct] = MFMA(g0, pF, accO[ct]);
        }
        __builtin_amdgcn_s_barrier();  // readers done -> next overwrite safe
        __builtin_amdgcn_sched_barrier(0);
    }
    // ph-pair reduction (o_red aliases buf region; o_lds after it)
    float* o_red = (float*)smem;                 // [64][68] f32 = 17408 B
    unsigned short* o_lds = smem + 8704;         // [64][72] bf16
    if (ph == 1) {
#pragma unroll
        for (int ct = 0; ct < 4; ++ct)
#pragma unroll
            for (int r = 0; r < 4; ++r) o_red[(ct * 16 + q * 4 + r) * 68 + nl] = accO[ct][r];
    }
    __syncthreads();
    if (ph == 0) {
#pragma unroll
        for (int ct = 0; ct < 4; ++ct) {
            us4 ov;
            ov.x = f2bf(accO[ct][0] + o_red[(ct * 16 + q * 4 + 0) * 68 + nl]);
            ov.y = f2bf(accO[ct][1] + o_red[(ct * 16 + q * 4 + 1) * 68 + nl]);
            ov.z = f2bf(accO[ct][2] + o_red[(ct * 16 + q * 4 + 2) * 68 + nl]);
            ov.w = f2bf(accO[ct][3] + o_red[(ct * 16 + q * 4 + 3) * 68 + nl]);
            *(us4*)&o_lds[nl * 72 + ct * 16 + q * 4] = ov;
        }
    }
    __syncthreads();
    // epilogue: finalT[o][n] = wmask @ outT + x ; o-rows split across ph
    bf8 oB0 = *(const bf8*)&o_lds[nl * 72 + q * 8];
    bf8 oB1 = *(const bf8*)&o_lds[nl * 72 + 32 + q * 8];
#pragma unroll
    for (int t2 = 0; t2 < 2; ++t2) {
        int tr = ph * 2 + t2;
        const unsigned short* wa = wmask_bf + (tr * 16 + l16) * 64 + q * 8;
        bf8 w0 = *(const bf8*)wa;
        bf8 w1 = *(const bf8*)(wa + 32);
        f4 accF = {0.f, 0.f, 0.f, 0.f};
        accF = MFMA(w0, oB0, accF);
        accF = MFMA(w1, oB1, accF);
#pragma unroll
        for (int r = 0; r < 4; ++r) {
            size_t ix = bo + (size_t)(tr * 16 + q * 4 + r) * NN + n0 + nl;
            out[ix] = accF[r] + x[ix];
        }
    }
}

// ---------------------------------------------------------------------------
extern "C" void kernel_launch(void* const* d_in, const int* in_sizes, int n_in,
                              void* d_out, int out_size, void* d_ws, size_t ws_size,
                              hipStream_t stream) {
    const float* x       = (const float*)d_in[0];
    const float* w_phi   = (const float*)d_in[1];
    const float* w_theta = (const float*)d_in[2];
    const float* w_g     = (const float*)d_in[3];
    const float* w_mask  = (const float*)d_in[4];
    const float* w_mv    = (const float*)d_in[5];
    const float* w_mk    = (const float*)d_in[6];
    float* out = (float*)d_out;

    const size_t CN = (size_t)BB * CC * NN;  // 2,097,152 elements
    char* p = (char*)d_ws;
    unsigned short* theta_nc = (unsigned short*)p; p += CN * 2;
    unsigned short* phi_cm = (unsigned short*)p;   p += CN * 2;
    unsigned short* g2_cm = (unsigned short*)p;    p += CN * 2;
    float* sinv = (float*)p;                       p += CN * 2;  // uses 128 KB of slot
    unsigned short* phi2t = (unsigned short*)p;    p += CN * 2;
    unsigned short* wmk_bf = (unsigned short*)p;   p += (size_t)NN * NN * 2;
    unsigned short* wcat_bf = (unsigned short*)p;  p += 192 * 64 * 2;
    unsigned short* wmask_bf = (unsigned short*)p; p += 4096 * 2;

    k0_prep<<<1040, 256, 0, stream>>>(w_mv, w_g, w_theta, w_phi, w_mask, w_mk,
                                      wcat_bf, wmask_bf, wmk_bf);
    k1_channel<<<dim3(32, BB), 256, 0, stream>>>(x, wcat_bf, theta_nc, phi_cm, g2_cm);
    k23_phi2_stats<<<512, 512, 0, stream>>>(phi_cm, wmk_bf, theta_nc, phi2t, sinv);
    k4_out<<<512, 512, 0, stream>>>(theta_nc, phi2t, g2_cm, sinv, wmask_bf, x, out);
}